// Round 1
// baseline (414.273 us; speedup 1.0000x reference)
//
#include <hip/hip_runtime.h>
#include <hip/hip_bf16.h>
#include <cstdint>

// DifferentiableILP on MI355X.
// Reference math: A = softmax(rule_weights[:,0,:]) (rows are prob. distributions)
//   3x: facts = max(facts, colmax(A @ facts))
// Since the update is a per-column scalar m(c), facts_k = max(init, m_{k-1}(c)):
// columns are independent -> each block owns a 64-column stripe and runs all
// iterations locally (no grid sync). bf16 MFMA (16x16x32, verified layouts),
// fp32 accumulate; tolerance 2e-2 >> bf16 error (~0.004-0.01).

typedef __attribute__((ext_vector_type(8))) short bf16x8;   // 8 bf16 = 4 VGPRs
typedef __attribute__((ext_vector_type(4))) float f32x4;
typedef unsigned short ushort_t;
typedef unsigned int uint32;

#define PDIM 512
#define CDIM 65536
#define NT   64      // columns per block

__device__ __forceinline__ ushort_t f2bf(float x) {          // RNE float->bf16
    uint32 u = __float_as_uint(x);
    return (ushort_t)((u + 0x7fffu + ((u >> 16) & 1u)) >> 16);
}
__device__ __forceinline__ float bf2f(uint32 bits) { return __uint_as_float(bits << 16); }

// ---------------- phase 1: A_bf16[r][p] = softmax over p of rule_weights[r][0][p]
__global__ __launch_bounds__(64) void softmax_kernel(const float* __restrict__ rw,
                                                     ushort_t* __restrict__ A) {
    const int r = blockIdx.x;
    const int lane = threadIdx.x;
    const float4* row = (const float4*)(rw + (size_t)r * PDIM);
    float4 a = row[lane];        // elems 4*lane .. +3
    float4 b = row[lane + 64];   // elems 256+4*lane .. +3
    float v[8] = {a.x, a.y, a.z, a.w, b.x, b.y, b.z, b.w};

    float mx = -1e30f;
    #pragma unroll
    for (int i = 0; i < 8; ++i) mx = fmaxf(mx, v[i]);
    #pragma unroll
    for (int d = 1; d < 64; d <<= 1) mx = fmaxf(mx, __shfl_xor(mx, d, 64));

    float s = 0.f;
    #pragma unroll
    for (int i = 0; i < 8; ++i) { v[i] = __expf(v[i] - mx); s += v[i]; }
    #pragma unroll
    for (int d = 1; d < 64; d <<= 1) s += __shfl_xor(s, d, 64);
    const float inv = 1.f / s;

    ushort_t o[8];
    #pragma unroll
    for (int i = 0; i < 8; ++i) o[i] = f2bf(v[i] * inv);
    uint2 w0, w1;
    w0.x = (uint32)o[0] | ((uint32)o[1] << 16);
    w0.y = (uint32)o[2] | ((uint32)o[3] << 16);
    w1.x = (uint32)o[4] | ((uint32)o[5] << 16);
    w1.y = (uint32)o[6] | ((uint32)o[7] << 16);
    *(uint2*)(A + (size_t)r * PDIM + 4 * lane)       = w0;
    *(uint2*)(A + (size_t)r * PDIM + 256 + 4 * lane) = w1;
}

// ---------------- phase 2: per-64-column stripe, fused 3-iteration fixpoint
// LDS ft[c][p] bf16, 16B-granule XOR swizzle: granule g of row c lives at g^(c&7).
// Exactly 64 KB static LDS -> 2 blocks/CU.
__global__ __launch_bounds__(256, 2) void ilp_kernel(
        const float* __restrict__ facts,
        const ushort_t* __restrict__ Abf,
        int* __restrict__ gm,              // [grid*NT], 0xAA poison = negative int = -inf init
        const int* __restrict__ n_iter_p,
        float* __restrict__ out) {
    __shared__ ushort_t ft[NT * PDIM];     // 65536 B

    const int tid  = threadIdx.x;
    const int wave = tid >> 6;
    const int lane = tid & 63;
    const int l15  = lane & 15;
    const int quad = lane >> 4;
    const int c0   = blockIdx.x * NT;
    int* gmb = gm + blockIdx.x * NT;

    // ---- stage: ft[c][p] = bf16(facts[p][c0+c]), swizzled, b128 LDS writes
    {
        const int c  = tid & 63;           // wave-coherent: lanes 0..63 -> cols 0..63 (coalesced)
        const int pb = tid >> 6;
        for (int s = 0; s < 16; ++s) {
            const int p0 = s * 32 + pb * 8;
            ushort_t g[8];
            #pragma unroll
            for (int i = 0; i < 8; ++i)
                g[i] = f2bf(facts[(size_t)(p0 + i) * CDIM + c0 + c]);
            const int gidx = (p0 >> 3) ^ (c & 7);
            *(int4*)(&ft[c * PDIM + gidx * 8]) = *(const int4*)g;
        }
    }
    __syncthreads();

    int n_iter = *n_iter_p;
    n_iter = n_iter < 0 ? 0 : (n_iter > 8 ? 8 : n_iter);   // safety clamp

    #pragma unroll 1
    for (int it = 0; it < n_iter; ++it) {
        float mx[4] = {-1e30f, -1e30f, -1e30f, -1e30f};

        #pragma unroll 1
        for (int pass = 0; pass < 2; ++pass) {
            const int r_base = pass * 256 + wave * 64;   // this wave's 64 rows
            f32x4 acc[4][4];
            #pragma unroll
            for (int rt = 0; rt < 4; ++rt)
                #pragma unroll
                for (int ct = 0; ct < 4; ++ct) acc[rt][ct] = (f32x4){0.f, 0.f, 0.f, 0.f};

            #pragma unroll 2
            for (int k0 = 0; k0 < PDIM; k0 += 32) {
                bf16x8 aF[4], bF[4];
                #pragma unroll
                for (int rt = 0; rt < 4; ++rt) {   // A[m][k]: m=lane&15, k=quad*8+j (verified m120)
                    const ushort_t* ap = Abf + (size_t)(r_base + rt * 16 + l15) * PDIM + k0 + quad * 8;
                    aF[rt] = *(const bf16x8*)ap;   // global_load_dwordx4, L2-resident
                }
                #pragma unroll
                for (int ct = 0; ct < 4; ++ct) {   // B[k][n]: n=lane&15, k=quad*8+j
                    const int c = ct * 16 + l15;
                    const int gidx = ((k0 >> 3) + quad) ^ (c & 7);
                    bF[ct] = *(const bf16x8*)(&ft[c * PDIM + gidx * 8]);  // ds_read_b128, swizzle-clean
                }
                #pragma unroll
                for (int rt = 0; rt < 4; ++rt)
                    #pragma unroll
                    for (int ct = 0; ct < 4; ++ct)
                        acc[rt][ct] = __builtin_amdgcn_mfma_f32_16x16x32_bf16(
                            aF[rt], bF[ct], acc[rt][ct], 0, 0, 0);
            }
            // fold this pass's 64 rows into per-lane colmax (D: col=lane&15, row=quad*4+reg)
            #pragma unroll
            for (int ct = 0; ct < 4; ++ct)
                #pragma unroll
                for (int rt = 0; rt < 4; ++rt)
                    #pragma unroll
                    for (int e = 0; e < 4; ++e)
                        mx[ct] = fmaxf(mx[ct], acc[rt][ct][e]);
        }

        // cross-quad (rows) reduce: lanes differing in bits 4,5
        #pragma unroll
        for (int ct = 0; ct < 4; ++ct) {
            mx[ct] = fmaxf(mx[ct], __shfl_xor(mx[ct], 16, 64));
            mx[ct] = fmaxf(mx[ct], __shfl_xor(mx[ct], 32, 64));
        }
        // cross-wave combine via global atomicMax on int (all values >= 0; poison is negative;
        // m monotone across iterations so no reset needed)
        if (quad == 0) {
            #pragma unroll
            for (int ct = 0; ct < 4; ++ct)
                atomicMax(&gmb[ct * 16 + l15], __float_as_int(mx[ct]));
        }
        __syncthreads();   // drains vmcnt -> atomics complete at L2 before reads

        // read m(c) and update ft[c][:] = max(ft, bf16(m)) (ushort max valid: nonneg bf16)
        {
            const int c = tid >> 2;
            const int mbits = atomicMax(&gmb[c], (int)0x80000000);  // pure read via RMW(INT_MIN)
            const ushort_t mb = f2bf(__int_as_float(mbits));
            const uint32 ml = (uint32)mb;
            const int gbase = tid & 3;
            #pragma unroll 1
            for (int g4 = 0; g4 < 16; ++g4) {
                const int gidx = (gbase + g4 * 4) ^ (c & 7);
                uint32* ptr = (uint32*)(&ft[c * PDIM + gidx * 8]);
                #pragma unroll
                for (int q = 0; q < 4; ++q) {
                    uint32 v = ptr[q];
                    uint32 lo = v & 0xffffu, hi = v >> 16;
                    lo = lo > ml ? lo : ml;
                    hi = hi > ml ? hi : ml;
                    ptr[q] = lo | (hi << 16);
                }
            }
        }
        __syncthreads();
    }

    // ---- epilogue: out[p][c0+c] = fp32(ft[c][p]); coalesced 256B stores per row
    {
        const int c  = tid & 63;
        const int pb = tid >> 6;
        for (int s = 0; s < 16; ++s) {
            const int p0 = s * 32 + pb * 8;
            const int gidx = (p0 >> 3) ^ (c & 7);
            ushort_t g[8];
            *(int4*)g = *(const int4*)(&ft[c * PDIM + gidx * 8]);
            #pragma unroll
            for (int i = 0; i < 8; ++i)
                out[(size_t)(p0 + i) * CDIM + c0 + c] = bf2f(g[i]);
        }
    }
}

extern "C" void kernel_launch(void* const* d_in, const int* in_sizes, int n_in,
                              void* d_out, int out_size, void* d_ws, size_t ws_size,
                              hipStream_t stream) {
    const float* facts    = (const float*)d_in[0];       // [512, 65536] fp32
    const float* rw       = (const float*)d_in[1];       // [512, 1, 512] fp32
    const int*   n_iter_p = (const int*)d_in[2];         // scalar 3
    float* out = (float*)d_out;

    ushort_t* A  = (ushort_t*)d_ws;                                  // 512 KB
    int*      gm = (int*)((char*)d_ws + (size_t)PDIM * PDIM * 2);    // 256 KB

    softmax_kernel<<<PDIM, 64, 0, stream>>>(rw, A);
    ilp_kernel<<<CDIM / NT, 256, 0, stream>>>(facts, A, gm, n_iter_p, out);
}

// Round 2
// 332.495 us; speedup vs baseline: 1.2460x; 1.2460x over previous
//
#include <hip/hip_runtime.h>
#include <hip/hip_bf16.h>
#include <cstdint>

// DifferentiableILP on MI355X (gfx950).
// A = softmax(rule_weights[:,0,:]); 3x: facts = max(facts, colmax(A @ facts)).
// Update adds only a per-column scalar m(c) -> columns independent -> each block
// owns a 64-col stripe, runs all iterations locally. bf16 MFMA 16x16x32,
// fp32 accumulate (tol 2e-2 >> bf16 error ~0.004).
//
// R2 changes vs R1 (262us, MfmaUtil 16%, latency-bound):
//  - A repacked fragment-linear: Apk[kt][rtile][lane] -> aF loads are contiguous
//    1KB dwordx4 (1 addr + imm offsets), not 16-line gathers.
//  - Single pass of 128 rows/wave: acc[8][4] (AGPR), 32 MFMA per k-step from
//    8 aF + 4 bF; aF double-buffered across k-steps.
//  - Update loop: conflict-free b128 granule RMW (xor-spread), packed u16 max.
//  - Last-iteration m folded into epilogue (skips one ft rewrite).

typedef __attribute__((ext_vector_type(8))) short bf16x8;   // 8 bf16 = 4 VGPRs
typedef __attribute__((ext_vector_type(4))) float f32x4;
typedef unsigned short ushort_t;
typedef unsigned int uint32;

#define PDIM 512
#define CDIM 65536
#define NT   64      // columns per block

__device__ __forceinline__ ushort_t f2bf(float x) {          // RNE float->bf16
    uint32 u = __float_as_uint(x);
    return (ushort_t)((u + 0x7fffu + ((u >> 16) & 1u)) >> 16);
}
__device__ __forceinline__ float bf2f(uint32 bits) { return __uint_as_float(bits << 16); }

// ---- phase 1: softmax row r, written directly in MFMA-fragment-linear layout:
// Apk 16B-chunk index idx16 = kt*2048 + rg*64 + (quad*16 + m)
//   holds A[rg*16 + m][kt*32 + quad*8 .. +7] as 8 bf16.
__global__ __launch_bounds__(64) void softmax_pack(const float* __restrict__ rw,
                                                   ushort_t* __restrict__ Apk) {
    const int r  = blockIdx.x;
    const int ln = threadIdx.x;
    const float* row = rw + r * PDIM;
    float4 x0 = *(const float4*)(row + ln * 8);
    float4 x1 = *(const float4*)(row + ln * 8 + 4);
    float v[8] = {x0.x, x0.y, x0.z, x0.w, x1.x, x1.y, x1.z, x1.w};

    float mx = -1e30f;
    #pragma unroll
    for (int i = 0; i < 8; ++i) mx = fmaxf(mx, v[i]);
    #pragma unroll
    for (int d = 1; d < 64; d <<= 1) mx = fmaxf(mx, __shfl_xor(mx, d, 64));
    float s = 0.f;
    #pragma unroll
    for (int i = 0; i < 8; ++i) { v[i] = __expf(v[i] - mx); s += v[i]; }
    #pragma unroll
    for (int d = 1; d < 64; d <<= 1) s += __shfl_xor(s, d, 64);
    const float inv = 1.f / s;

    ushort_t o[8];
    #pragma unroll
    for (int i = 0; i < 8; ++i) o[i] = f2bf(v[i] * inv);
    // this lane holds elements p = ln*8 .. +7  ->  kt = ln>>2, quad = ln&3
    const int idx16 = (ln >> 2) * 2048 + (r >> 4) * 64 + ((ln & 3) << 4) + (r & 15);
    *(int4*)(Apk + idx16 * 8) = *(const int4*)o;
}

// ---- phase 2: per-64-column stripe, fused multi-iteration fixpoint.
// LDS ft[c][p] bf16, 16B-granule XOR swizzle: logical granule g of row c at slot g^(c&7).
__global__ __launch_bounds__(256, 2) void ilp_kernel(
        const float* __restrict__ facts,
        const ushort_t* __restrict__ Apk,
        int* __restrict__ gm,              // [grid*NT] float-as-int colmax scratch
        const int* __restrict__ n_iter_p,
        float* __restrict__ out) {
    __shared__ ushort_t ft[NT * PDIM];     // exactly 65536 B -> 2 blocks/CU

    const int tid  = threadIdx.x;
    const int wave = tid >> 6;
    const int lane = tid & 63;
    const int l15  = lane & 15;
    const int quad = lane >> 4;
    const int c0   = blockIdx.x * NT;
    int* gmb = gm + blockIdx.x * NT;

    // ---- stage: ft[c][p] = bf16(facts[p][c0+c]); init gm
    {
        if (tid < NT) gmb[tid] = (int)0x80000000;   // -0.0f: identity for nonneg fmax
        const int c  = tid & 63;                    // lanes -> cols: coalesced 256B/inst
        const int pb = tid >> 6;
        for (int s = 0; s < 16; ++s) {
            const int p0 = s * 32 + pb * 8;
            ushort_t g[8];
            #pragma unroll
            for (int i = 0; i < 8; ++i)
                g[i] = f2bf(facts[(p0 + i) * CDIM + c0 + c]);
            const int gidx = (p0 >> 3) ^ (c & 7);
            *(int4*)(&ft[c * PDIM + gidx * 8]) = *(const int4*)g;
        }
    }
    __syncthreads();

    int n_iter = *n_iter_p;
    n_iter = n_iter < 0 ? 0 : (n_iter > 8 ? 8 : n_iter);

    // per-wave GEMM bases (32-bit element offsets)
    const int abase = wave * 4096 + lane * 8;        // + kt*16384 + rt*512
    int cbase[4], cx8[4];
    #pragma unroll
    for (int ct = 0; ct < 4; ++ct) {
        const int c = ct * 16 + l15;
        cbase[ct] = c * PDIM;
        cx8[ct]   = (c & 7) * 8;                     // element-scaled xor key
    }

    #pragma unroll 1
    for (int it = 0; it < n_iter; ++it) {
        // ---- GEMM: this wave accumulates rows wave*128 + rt*16 .. (128 rows)
        f32x4 acc[8][4];
        #pragma unroll
        for (int rt = 0; rt < 8; ++rt)
            #pragma unroll
            for (int ct = 0; ct < 4; ++ct) acc[rt][ct] = (f32x4){0.f, 0.f, 0.f, 0.f};

        bf16x8 aF[2][8];
        {   // prefetch kt=0
            const ushort_t* ap = Apk + abase;
            #pragma unroll
            for (int rt = 0; rt < 8; ++rt) aF[0][rt] = *(const bf16x8*)(ap + rt * 512);
        }

        #pragma unroll 2
        for (int kt = 0; kt < 16; ++kt) {
            const int cur = kt & 1, nxt = cur ^ 1;
            bf16x8 bF[4];
            const int g8 = (kt * 4 + quad) * 8;
            #pragma unroll
            for (int ct = 0; ct < 4; ++ct)
                bF[ct] = *(const bf16x8*)(&ft[cbase[ct] + (g8 ^ cx8[ct])]);  // ds_read_b128

            {   // prefetch next k-step's A (wraps harmlessly at kt=15)
                const ushort_t* ap = Apk + abase + (((kt + 1) & 15) * 16384);
                #pragma unroll
                for (int rt = 0; rt < 8; ++rt) aF[nxt][rt] = *(const bf16x8*)(ap + rt * 512);
            }

            #pragma unroll
            for (int rt = 0; rt < 8; ++rt)
                #pragma unroll
                for (int ct = 0; ct < 4; ++ct)
                    acc[rt][ct] = __builtin_amdgcn_mfma_f32_16x16x32_bf16(
                        aF[cur][rt], bF[ct], acc[rt][ct], 0, 0, 0);
        }

        // ---- colmax fold (D: col=lane&15, row=quad*4+e)
        float mx[4] = {-1e30f, -1e30f, -1e30f, -1e30f};
        #pragma unroll
        for (int ct = 0; ct < 4; ++ct) {
            #pragma unroll
            for (int rt = 0; rt < 8; ++rt)
                #pragma unroll
                for (int e = 0; e < 4; ++e)
                    mx[ct] = fmaxf(mx[ct], acc[rt][ct][e]);
            mx[ct] = fmaxf(mx[ct], __shfl_xor(mx[ct], 16, 64));
            mx[ct] = fmaxf(mx[ct], __shfl_xor(mx[ct], 32, 64));
        }
        if (quad == 0) {
            #pragma unroll
            for (int ct = 0; ct < 4; ++ct)
                atomicMax(&gmb[ct * 16 + l15], __float_as_int(mx[ct]));  // m >= 0, monotone
        }
        __syncthreads();   // vmcnt drained before barrier -> atomics visible

        // ---- ft = max(ft, bf16(m)) — skip on last iter (folded into epilogue)
        if (it < n_iter - 1) {
            const int c = tid & 63;
            const int mbits = atomicMax(&gmb[c], (int)0x80000000);  // L1-bypassing read
            const uint32 ml = (uint32)f2bf(__int_as_float(mbits));
            #pragma unroll 1
            for (int j = 0; j < 16; ++j) {
                const int slot = (wave + 4 * j) ^ (c & 7);          // conflict-free spread
                uint32* ptr = (uint32*)(&ft[c * PDIM + slot * 8]);
                uint4 v = *(uint4*)ptr;
                uint32* w = (uint32*)&v;
                #pragma unroll
                for (int q = 0; q < 4; ++q) {
                    uint32 lo = w[q] & 0xffffu, hi = w[q] >> 16;    // nonneg bf16: u16 cmp ok
                    lo = lo > ml ? lo : ml;
                    hi = hi > ml ? hi : ml;
                    w[q] = lo | (hi << 16);
                }
                *(uint4*)ptr = v;
            }
            __syncthreads();
        }
    }

    // ---- epilogue: out = max(ft, m_final); coalesced 256B stores
    {
        const int c  = tid & 63;
        const int pb = tid >> 6;
        const int mbits = atomicMax(&gmb[c], (int)0x80000000);
        const float m = __int_as_float(mbits);     // -0.0f if n_iter==0 (identity)
        for (int s = 0; s < 16; ++s) {
            const int p0 = s * 32 + pb * 8;
            const int gidx = (p0 >> 3) ^ (c & 7);
            ushort_t g[8];
            *(int4*)g = *(const int4*)(&ft[c * PDIM + gidx * 8]);
            #pragma unroll
            for (int i = 0; i < 8; ++i)
                out[(p0 + i) * CDIM + c0 + c] = fmaxf(bf2f(g[i]), m);
        }
    }
}

extern "C" void kernel_launch(void* const* d_in, const int* in_sizes, int n_in,
                              void* d_out, int out_size, void* d_ws, size_t ws_size,
                              hipStream_t stream) {
    const float* facts    = (const float*)d_in[0];       // [512, 65536] fp32
    const float* rw       = (const float*)d_in[1];       // [512, 1, 512] fp32
    const int*   n_iter_p = (const int*)d_in[2];         // scalar 3
    float* out = (float*)d_out;

    ushort_t* Apk = (ushort_t*)d_ws;                                 // 512 KB
    int*      gm  = (int*)((char*)d_ws + (size_t)PDIM * PDIM * 2);   // 256 KB

    softmax_pack<<<PDIM, 64, 0, stream>>>(rw, Apk);
    ilp_kernel<<<CDIM / NT, 256, 0, stream>>>(facts, Apk, gm, n_iter_p, out);
}